// Round 11
// baseline (183.256 us; speedup 1.0000x reference)
//
#include <hip/hip_runtime.h>
#include <hip/hip_bf16.h>
#include <math.h>

typedef __bf16 bf16_t;
typedef __bf16 bf8 __attribute__((ext_vector_type(8)));
typedef __bf16 bf4 __attribute__((ext_vector_type(4)));
typedef float f32x4 __attribute__((ext_vector_type(4)));
typedef int i32x8 __attribute__((ext_vector_type(8)));
typedef unsigned char u8;

#define AS1 __attribute__((address_space(1)))
#define AS3 __attribute__((address_space(3)))

#define B_ROWS 4096
#define NTOT   8192
#define DIN    1024
#define DENC   512
#define DH     256
#define DP     128
#define NSLICE 32
#define INV_T        14.285714285714286f   // 1/0.07
#define SCALE_LOG2   20.609929155556620f   // log2(e)/0.07

__device__ __forceinline__ f32x4 mfma_16x16x32(bf8 a, bf8 b, f32x4 c) {
  return __builtin_amdgcn_mfma_f32_16x16x32_bf16(a, b, c, 0, 0, 0);
}

// ---------------------------------------------------------------------------
// prep: weight transposes ONLY (336 blocks) — the x f32->bf16 cast is gone;
// the encoder now stages f32 x directly and converts at LDS-read.
// ---------------------------------------------------------------------------
__global__ __launch_bounds__(256) void prep_kernel(
    const float* __restrict__ We_i, const float* __restrict__ We_t,
    const float* __restrict__ W1_i, const float* __restrict__ W1_t,
    const float* __restrict__ W2_i, const float* __restrict__ W2_t,
    bf16_t* __restrict__ Wet_i, bf16_t* __restrict__ Wet_t,
    bf16_t* __restrict__ W1t_i, bf16_t* __restrict__ W1t_t,
    bf16_t* __restrict__ W2t_i, bf16_t* __restrict__ W2t_t) {
  const int b = blockIdx.x;
  const int tid = threadIdx.x;
  const float* src; bf16_t* dst; int K, N, tile;
  if (b < 128)      { src = We_i; dst = Wet_i; K = 1024; N = 512; tile = b; }
  else if (b < 256) { src = We_t; dst = Wet_t; K = 1024; N = 512; tile = b - 128; }
  else if (b < 288) { src = W1_i; dst = W1t_i; K = 512;  N = 256; tile = b - 256; }
  else if (b < 320) { src = W1_t; dst = W1t_t; K = 512;  N = 256; tile = b - 288; }
  else if (b < 328) { src = W2_i; dst = W2t_i; K = 256;  N = 128; tile = b - 320; }
  else              { src = W2_t; dst = W2t_t; K = 256;  N = 128; tile = b - 328; }
  const int tilesN = N >> 6;
  const int k0 = (tile / tilesN) * 64;
  const int n0 = (tile % tilesN) * 64;

  __shared__ float ld[64][65];
  #pragma unroll
  for (int i = 0; i < 4; ++i) {
    int cid = tid + i * 256;
    int r = cid >> 4;
    int c = (cid & 15) * 4;
    float4 v = *(const float4*)(src + (size_t)(k0 + r) * N + n0 + c);
    ld[r][c + 0] = v.x; ld[r][c + 1] = v.y; ld[r][c + 2] = v.z; ld[r][c + 3] = v.w;
  }
  __syncthreads();
  #pragma unroll
  for (int i = 0; i < 2; ++i) {
    int cid = tid + i * 256;
    int rn = cid >> 3;
    int c8 = (cid & 7) * 8;
    bf8 w;
    #pragma unroll
    for (int j = 0; j < 8; ++j) w[j] = (bf16_t)ld[c8 + j][rn];
    *(bf8*)(dst + (size_t)(n0 + rn) * K + k0 + c8) = w;
  }
}

// ---------------------------------------------------------------------------
// enc_gemm: h = x @ We + be with FUSED f32->bf16 cast. A (x) is staged as
// f32 via glds (tile 128x32 f32 = 16 KB/buf) with XOR chunk swizzle
// c^(row&7) — breaks the 128 B row stride (16-way bank alias) while keeping
// the glds lane-contiguous dest. Converted to bf16 at LDS-read (same RNE
// cast the old prep did -> bit-identical h). B (Wet) staged bf16 as before.
// MT=128, NT=64, BK=32, double-buffered issue-ahead. Paired via blockIdx.z.
// ---------------------------------------------------------------------------
__global__ __launch_bounds__(256) void enc_gemm(
    const float* __restrict__ A0, const float* __restrict__ A1,
    const bf16_t* __restrict__ B0, const bf16_t* __restrict__ B1,
    const float* __restrict__ bias0, const float* __restrict__ bias1,
    bf16_t* __restrict__ out0, bf16_t* __restrict__ out1) {
  const float* A    = blockIdx.z ? A1 : A0;
  const bf16_t* Bt  = blockIdx.z ? B1 : B0;
  const float* bias = blockIdx.z ? bias1 : bias0;
  bf16_t* outp      = blockIdx.z ? out1 : out0;
  const int K = DIN, N = DENC;

  const int nb   = blockIdx.x * 64;
  const int mb   = blockIdx.y * 128;
  const int tid  = threadIdx.x;
  const int wave = tid >> 6;
  const int lane = tid & 63;
  const int l15  = lane & 15;
  const int quad = lane >> 4;

  __shared__ __align__(16) float  Asb[2][128 * 32];   // f32 staging
  __shared__ __align__(16) bf16_t Bsb[2][64 * 32];

  f32x4 acc[2][4];
  #pragma unroll
  for (int i = 0; i < 2; ++i)
    #pragma unroll
    for (int j = 0; j < 4; ++j) acc[i][j] = (f32x4){0.f, 0.f, 0.f, 0.f};

  auto stage = [&](int k0, int pb) {
    #pragma unroll
    for (int i = 0; i < 4; ++i) {          // A: 1024 slots of 16B (4 f32)
      const int s   = i * 256 + tid;
      const int row = s >> 3;
      const int cf  = (s & 7) ^ (row & 7); // XOR chunk swizzle
      const float* ga = A + (size_t)(mb + row) * K + k0 + cf * 4;
      __builtin_amdgcn_global_load_lds(
          (const AS1 void*)ga,
          (AS3 void*)(Asb[pb] + (size_t)(i * 256 + wave * 64) * 4), 16, 0, 0);
    }
    {                                      // B: 256 slots of 16B (8 bf16)
      const bf16_t* gb = Bt + (size_t)(nb + (tid >> 2)) * K + k0 + (tid & 3) * 8;
      __builtin_amdgcn_global_load_lds(
          (const AS1 void*)gb,
          (AS3 void*)(Bsb[pb] + (size_t)(wave * 64) * 8), 16, 0, 0);
    }
  };

  stage(0, 0);
  const int T = K >> 5;                    // 32 steps
  for (int t = 0; t < T; ++t) {
    __syncthreads();                       // tile t visible; compute(t-1) done
    if (t + 1 < T) stage((t + 1) << 5, (t + 1) & 1);
    const float*  as = Asb[t & 1];
    const bf16_t* bs = Bsb[t & 1];
    bf8 a[2];
    #pragma unroll
    for (int c = 0; c < 2; ++c) {
      const int row = wave * 32 + c * 16 + l15;
      const float* ar = as + (size_t)row * 32;
      float4 f0 = *(const float4*)(ar + (((2 * quad)     ^ (row & 7)) * 4));
      float4 f1 = *(const float4*)(ar + (((2 * quad + 1) ^ (row & 7)) * 4));
      a[c][0] = (bf16_t)f0.x; a[c][1] = (bf16_t)f0.y;
      a[c][2] = (bf16_t)f0.z; a[c][3] = (bf16_t)f0.w;
      a[c][4] = (bf16_t)f1.x; a[c][5] = (bf16_t)f1.y;
      a[c][6] = (bf16_t)f1.z; a[c][7] = (bf16_t)f1.w;
    }
    #pragma unroll
    for (int nt = 0; nt < 4; ++nt) {
      bf8 bb = *(const bf8*)(bs + (size_t)(nt * 16 + l15) * 32 + quad * 8);
      acc[0][nt] = mfma_16x16x32(a[0], bb, acc[0][nt]);
      acc[1][nt] = mfma_16x16x32(a[1], bb, acc[1][nt]);
    }
  }

  #pragma unroll
  for (int c = 0; c < 2; ++c) {
    const int orow = mb + wave * 32 + c * 16 + quad * 4;
    #pragma unroll
    for (int nt = 0; nt < 4; ++nt) {
      const int ocol = nb + nt * 16 + l15;
      const float bval = bias[ocol];
      #pragma unroll
      for (int r = 0; r < 4; ++r)
        outp[(size_t)(orow + r) * N + ocol] = (bf16_t)(acc[c][nt][r] + bval);
    }
  }
}

// ---------------------------------------------------------------------------
// gemm_glds: bf16 GEMM (used for head 1), async staging, double-buffered
// issue-ahead. Tile: MT x 64, BK=32. Paired img/txt via blockIdx.z.
// ---------------------------------------------------------------------------
template<int MT, bool RELU>
__global__ __launch_bounds__(256) void gemm_glds(
    const bf16_t* __restrict__ A0, const bf16_t* __restrict__ A1,
    const bf16_t* __restrict__ B0, const bf16_t* __restrict__ B1,
    const float* __restrict__ bias0, const float* __restrict__ bias1,
    bf16_t* __restrict__ out0, bf16_t* __restrict__ out1,
    int N, int K) {
  const bf16_t* A   = blockIdx.z ? A1 : A0;
  const bf16_t* Bt  = blockIdx.z ? B1 : B0;
  const float* bias = blockIdx.z ? bias1 : bias0;
  bf16_t* outp      = blockIdx.z ? out1 : out0;

  const int nb   = blockIdx.x * 64;
  const int mb   = blockIdx.y * MT;
  const int tid  = threadIdx.x;
  const int wave = tid >> 6;
  const int lane = tid & 63;
  const int l15  = lane & 15;
  const int quad = lane >> 4;
  constexpr int CH = MT / 64;

  __shared__ __align__(16) bf16_t As[2][MT * 32];
  __shared__ __align__(16) bf16_t Bs[2][64 * 32];

  f32x4 acc[CH][4];
  #pragma unroll
  for (int i = 0; i < CH; ++i)
    #pragma unroll
    for (int j = 0; j < 4; ++j) acc[i][j] = (f32x4){0.f, 0.f, 0.f, 0.f};

  auto stage = [&](int k0, int pb) {
    #pragma unroll
    for (int i = 0; i < CH; ++i) {
      const int s = tid + i * 256;
      const bf16_t* ga = A + (size_t)(mb + (s >> 2)) * K + k0 + (s & 3) * 8;
      __builtin_amdgcn_global_load_lds(
          (const AS1 void*)ga,
          (AS3 void*)(As[pb] + (size_t)(wave * 64 + i * 256) * 8), 16, 0, 0);
    }
    const bf16_t* gb = Bt + (size_t)(nb + (tid >> 2)) * K + k0 + (tid & 3) * 8;
    __builtin_amdgcn_global_load_lds(
        (const AS1 void*)gb,
        (AS3 void*)(Bs[pb] + (size_t)(wave * 64) * 8), 16, 0, 0);
  };

  stage(0, 0);
  const int T = K >> 5;
  for (int t = 0; t < T; ++t) {
    __syncthreads();
    if (t + 1 < T) stage((t + 1) << 5, (t + 1) & 1);
    const bf16_t* as = As[t & 1];
    const bf16_t* bs = Bs[t & 1];
    bf8 a[CH];
    #pragma unroll
    for (int i = 0; i < CH; ++i)
      a[i] = *(const bf8*)(as + (size_t)(wave * (16 * CH) + i * 16 + l15) * 32 + quad * 8);
    #pragma unroll
    for (int nt = 0; nt < 4; ++nt) {
      bf8 bb = *(const bf8*)(bs + (size_t)(nt * 16 + l15) * 32 + quad * 8);
      #pragma unroll
      for (int i = 0; i < CH; ++i)
        acc[i][nt] = mfma_16x16x32(a[i], bb, acc[i][nt]);
    }
  }

  #pragma unroll
  for (int i = 0; i < CH; ++i) {
    const int orow = mb + wave * (16 * CH) + i * 16 + quad * 4;
    #pragma unroll
    for (int nt = 0; nt < 4; ++nt) {
      const int ocol = nb + nt * 16 + l15;
      const float bval = bias[ocol];
      #pragma unroll
      for (int r = 0; r < 4; ++r) {
        float v = acc[i][nt][r] + bval;
        if (RELU) v = fmaxf(v, 0.f);
        outp[(size_t)(orow + r) * N + ocol] = (bf16_t)v;
      }
    }
  }
}

// ---------------------------------------------------------------------------
// head2_norm: z = g @ W2t^T + b2 (K=256, N=128) + fused L2 norm, emitting
// fp8 e4m3 reps8 DIRECTLY (same v_cvt_pk_fp8 RNE the old quant kernel used
// -> identical numerics; bf16 reps never materialized, quant dispatch gone).
// 16-row blocks (512 WGs), glds-staged A+B with XOR chunk swizzle,
// double-buffered issue-ahead. Wave w covers cols w*32..w*32+31.
// ---------------------------------------------------------------------------
__global__ __launch_bounds__(256) void head2_norm(
    const bf16_t* __restrict__ A0, const bf16_t* __restrict__ A1,
    const bf16_t* __restrict__ B0, const bf16_t* __restrict__ B1,
    const float* __restrict__ bias0, const float* __restrict__ bias1,
    u8* __restrict__ reps8) {
  const bf16_t* A   = blockIdx.z ? A1 : A0;
  const bf16_t* Bt  = blockIdx.z ? B1 : B0;
  const float* bias = blockIdx.z ? bias1 : bias0;

  const int mb   = blockIdx.x * 16;
  const int tid  = threadIdx.x;
  const int wave = tid >> 6;
  const int lane = tid & 63;
  const int l15  = lane & 15;
  const int quad = lane >> 4;
  const int wc0  = wave * 32;

  __shared__ __align__(16) bf16_t Asb[2][16 * 32];
  __shared__ __align__(16) bf16_t Bsb[2][128 * 32];
  __shared__ float ssL[64];                // [wave][row]

  f32x4 acc[2];
  acc[0] = (f32x4){0.f, 0.f, 0.f, 0.f};
  acc[1] = (f32x4){0.f, 0.f, 0.f, 0.f};

  auto stage = [&](int k0, int pb) {
    if (wave == 0) {                       // A: 64 slots of 16B
      const int row = lane >> 2, j = lane & 3, cf = j ^ (row & 3);
      const bf16_t* ga = A + (size_t)(mb + row) * DH + k0 + cf * 8;
      __builtin_amdgcn_global_load_lds(
          (const AS1 void*)ga, (AS3 void*)(Asb[pb]), 16, 0, 0);
    }
    #pragma unroll
    for (int i = 0; i < 2; ++i) {          // B: 512 slots of 16B
      const int s = wave * 64 + i * 256 + lane;
      const int col = s >> 2, j = s & 3, cf = j ^ (col & 3);
      const bf16_t* gb = Bt + (size_t)col * DH + k0 + cf * 8;
      __builtin_amdgcn_global_load_lds(
          (const AS1 void*)gb,
          (AS3 void*)(Bsb[pb] + (size_t)(wave * 64 + i * 256) * 8), 16, 0, 0);
    }
  };

  stage(0, 0);
  for (int t = 0; t < 8; ++t) {
    __syncthreads();
    if (t < 7) stage((t + 1) << 5, (t + 1) & 1);
    const bf16_t* as = Asb[t & 1];
    const bf16_t* bs = Bsb[t & 1];
    bf8 a = *(const bf8*)(as + (size_t)(l15 * 4 + (quad ^ (l15 & 3))) * 8);
    #pragma unroll
    for (int nt = 0; nt < 2; ++nt) {
      const int col = wc0 + nt * 16 + l15;
      bf8 bb = *(const bf8*)(bs + (size_t)(col * 4 + (quad ^ (col & 3))) * 8);
      acc[nt] = mfma_16x16x32(a, bb, acc[nt]);
    }
  }

  float ssp[4];
  #pragma unroll
  for (int r = 0; r < 4; ++r) {
    #pragma unroll
    for (int nt = 0; nt < 2; ++nt) acc[nt][r] += bias[wc0 + nt * 16 + l15];
    float s = acc[0][r] * acc[0][r] + acc[1][r] * acc[1][r];
    s += __shfl_xor(s, 1); s += __shfl_xor(s, 2);
    s += __shfl_xor(s, 4); s += __shfl_xor(s, 8);
    ssp[r] = s;
  }
  if (l15 == 0) {
    #pragma unroll
    for (int r = 0; r < 4; ++r) ssL[wave * 16 + quad * 4 + r] = ssp[r];
  }
  __syncthreads();
  const size_t gr0 = (size_t)(blockIdx.z ? B_ROWS : 0) + mb + quad * 4;
  #pragma unroll
  for (int r = 0; r < 4; ++r) {
    const int row = quad * 4 + r;
    float tot = ssL[row] + ssL[16 + row] + ssL[32 + row] + ssL[48 + row];
    const float inv = 1.0f / fmaxf(sqrtf(tot), 1e-12f);
    int pk = __builtin_amdgcn_cvt_pk_fp8_f32(acc[0][r] * inv, acc[1][r] * inv, 0, 0);
    reps8[(gr0 + r) * DP + wc0 + l15]      = (u8)(pk & 0xff);
    reps8[(gr0 + r) * DP + wc0 + 16 + l15] = (u8)((pk >> 8) & 0xff);
  }
}

// ---------------------------------------------------------------------------
// sim_fp8: fused reps8·reps8ᵀ + exp row-sums via MX-scaled fp8 MFMA
// (16x16x128, scales 1.0). 2-barrier LDS staging, 8 KB tiles, XOR swizzle.
// WG = 256 rows x 256-col slice, grid (32,32)=1024. Private Spart slots.
// ---------------------------------------------------------------------------
__global__ __launch_bounds__(256) void sim_fp8_kernel(
    const u8* __restrict__ reps8, float* __restrict__ Spart) {
  const int rowbase = blockIdx.y * 256;
  const int slice   = blockIdx.x;
  const int col0    = slice * 256;
  const int tid  = threadIdx.x;
  const int wave = tid >> 6;
  const int lane = tid & 63;
  const int l15  = lane & 15;
  const int quad = lane >> 4;

  __shared__ __align__(16) u8 Bs[2][64 * DP];   // 2 x 8 KB

  const int r0 = rowbase + wave * 64;
  i32x8 af[4];
  #pragma unroll
  for (int c = 0; c < 4; ++c) {
    const uint4* ap = (const uint4*)(reps8 + (size_t)(r0 + c * 16 + l15) * DP + quad * 32);
    uint4 x0 = ap[0], x1 = ap[1];
    af[c] = (i32x8){(int)x0.x, (int)x0.y, (int)x0.z, (int)x0.w,
                    (int)x1.x, (int)x1.y, (int)x1.z, (int)x1.w};
  }

  float rs[4][4];
  #pragma unroll
  for (int c = 0; c < 4; ++c)
    #pragma unroll
    for (int r = 0; r < 4; ++r) rs[c][r] = 0.f;

  for (int t = 0; t < 4; ++t) {
    u8* buf = Bs[t & 1];
    __syncthreads();
    const int jt0 = col0 + t * 64;
    #pragma unroll
    for (int i = 0; i < 2; ++i) {          // stage 8 KB: 512 slots of 16B
      const int s   = i * 256 + tid;
      const int col = s >> 3;
      const int cf  = (s & 7) ^ (col & 7);
      const u8* g = reps8 + (size_t)(jt0 + col) * DP + cf * 16;
      __builtin_amdgcn_global_load_lds(
          (const AS1 void*)g,
          (AS3 void*)(buf + (size_t)(i * 256 + wave * 64) * 16), 16, 0, 0);
    }
    __syncthreads();

    #pragma unroll
    for (int st = 0; st < 4; ++st) {
      const int coln = st * 16 + l15;
      const u8* cbase = buf + (size_t)coln * DP;
      const int c0 = ((2 * quad)     ^ (coln & 7)) * 16;
      const int c1 = ((2 * quad + 1) ^ (coln & 7)) * 16;
      uint4 b0 = *(const uint4*)(cbase + c0);
      uint4 b1 = *(const uint4*)(cbase + c1);
      i32x8 bf = (i32x8){(int)b0.x, (int)b0.y, (int)b0.z, (int)b0.w,
                         (int)b1.x, (int)b1.y, (int)b1.z, (int)b1.w};
      #pragma unroll
      for (int c = 0; c < 4; ++c) {
        f32x4 acc = (f32x4){0.f, 0.f, 0.f, 0.f};
        acc = __builtin_amdgcn_mfma_scale_f32_16x16x128_f8f6f4(
            af[c], bf, acc, 0, 0, 0, 0x7F7F7F7F, 0, 0x7F7F7F7F);
        #pragma unroll
        for (int r = 0; r < 4; ++r)
          rs[c][r] += __builtin_amdgcn_exp2f(acc[r] * SCALE_LOG2);
      }
    }
  }

  #pragma unroll
  for (int c = 0; c < 4; ++c) {
    const int i0 = r0 + c * 16 + quad * 4;
    #pragma unroll
    for (int r = 0; r < 4; ++r) {
      float v = rs[c][r];
      v += __shfl_xor(v, 1); v += __shfl_xor(v, 2);
      v += __shfl_xor(v, 4); v += __shfl_xor(v, 8);
      if (l15 == 0) Spart[(size_t)slice * NTOT + i0 + r] = v;
    }
  }
}

// ---------------------------------------------------------------------------
// rowfinal: one wave per row, no atomics/fences. dii/pos computed from the
// SAME fp8 values the MFMA consumed -> dominant e^{dii/t} cancels cleanly.
//   L_i = log(sum(parts) - exp(dii/t) + exp(pos/t)) - pos/t
// ---------------------------------------------------------------------------
__global__ __launch_bounds__(256) void rowfinal_kernel(
    const u8* __restrict__ reps8, const float* __restrict__ Spart,
    float* __restrict__ L) {
  const int tid  = threadIdx.x;
  const int wave = tid >> 6;
  const int lane = tid & 63;
  const int row  = blockIdx.x * 4 + wave;
  const int ua = *(const unsigned short*)(reps8 + (size_t)row * DP + lane * 2);
  const int ub = *(const unsigned short*)(reps8 + (size_t)(row ^ B_ROWS) * DP + lane * 2);
  float a0 = __builtin_amdgcn_cvt_f32_fp8(ua, 0);
  float a1 = __builtin_amdgcn_cvt_f32_fp8(ua, 1);
  float b0 = __builtin_amdgcn_cvt_f32_fp8(ub, 0);
  float b1 = __builtin_amdgcn_cvt_f32_fp8(ub, 1);
  float dii = a0 * a0 + a1 * a1;
  float pos = a0 * b0 + a1 * b1;
  float ps  = (lane < NSLICE) ? Spart[(size_t)lane * NTOT + row] : 0.f;
  #pragma unroll
  for (int m = 1; m < 64; m <<= 1) {
    dii += __shfl_xor(dii, m);
    pos += __shfl_xor(pos, m);
    ps  += __shfl_xor(ps, m);
  }
  if (lane == 0) {
    float Si = ps - __builtin_amdgcn_exp2f(dii * SCALE_LOG2)
                  + __builtin_amdgcn_exp2f(pos * SCALE_LOG2);
    L[row] = logf(Si) - pos * INV_T;
  }
}

// ---------------------------------------------------------------------------
// reduce: mean over 8192 per-row losses -> d_out[0]. Single block.
// ---------------------------------------------------------------------------
__global__ __launch_bounds__(1024) void reduce_kernel(
    const float* __restrict__ L, float* __restrict__ out) {
  const int tid = threadIdx.x;
  float acc = 0.f;
  for (int i = tid; i < NTOT; i += 1024) acc += L[i];
  #pragma unroll
  for (int m = 1; m < 64; m <<= 1) acc += __shfl_xor(acc, m);
  __shared__ float wsum[16];
  if ((tid & 63) == 0) wsum[tid >> 6] = acc;
  __syncthreads();
  if (tid < 16) {
    float v = wsum[tid];
    #pragma unroll
    for (int m = 1; m < 16; m <<= 1) v += __shfl_xor(v, m);
    if (tid == 0) out[0] = v * (1.0f / NTOT);
  }
}

// ---------------------------------------------------------------------------
extern "C" void kernel_launch(void* const* d_in, const int* in_sizes, int n_in,
                              void* d_out, int out_size, void* d_ws, size_t ws_size,
                              hipStream_t stream) {
  const float* x_img  = (const float*)d_in[0];
  const float* x_txt  = (const float*)d_in[1];
  const float* We_img = (const float*)d_in[2];
  const float* be_img = (const float*)d_in[3];
  const float* We_txt = (const float*)d_in[4];
  const float* be_txt = (const float*)d_in[5];
  const float* W1_img = (const float*)d_in[6];
  const float* b1_img = (const float*)d_in[7];
  const float* W2_img = (const float*)d_in[8];
  const float* b2_img = (const float*)d_in[9];
  const float* W1_txt = (const float*)d_in[10];
  const float* b1_txt = (const float*)d_in[11];
  const float* W2_txt = (const float*)d_in[12];
  const float* b2_txt = (const float*)d_in[13];

  char* p = (char*)d_ws;
  bf16_t* Wet_img = (bf16_t*)p; p += (size_t)DENC * DIN * 2;
  bf16_t* Wet_txt = (bf16_t*)p; p += (size_t)DENC * DIN * 2;
  bf16_t* W1t_img = (bf16_t*)p; p += (size_t)DH * DENC * 2;
  bf16_t* W1t_txt = (bf16_t*)p; p += (size_t)DH * DENC * 2;
  bf16_t* W2t_img = (bf16_t*)p; p += (size_t)DP * DH * 2;
  bf16_t* W2t_txt = (bf16_t*)p; p += (size_t)DP * DH * 2;
  bf16_t* h_img   = (bf16_t*)p; p += (size_t)B_ROWS * DENC * 2;
  bf16_t* h_txt   = (bf16_t*)p; p += (size_t)B_ROWS * DENC * 2;
  bf16_t* g_img   = (bf16_t*)p; p += (size_t)B_ROWS * DH * 2;
  bf16_t* g_txt   = (bf16_t*)p; p += (size_t)B_ROWS * DH * 2;
  u8*     reps8   = (u8*)    p; p += (size_t)NTOT * DP;
  float*  Spart   = (float*) p; p += (size_t)NSLICE * NTOT * 4;
  float*  L       = (float*) p; p += (size_t)NTOT * 4;

  // weight transposes only (x-cast is fused into enc_gemm)
  prep_kernel<<<336, 256, 0, stream>>>(
      We_img, We_txt, W1_img, W1_txt, W2_img, W2_txt,
      Wet_img, Wet_txt, W1t_img, W1t_txt, W2t_img, W2t_txt);

  // encoder: h = x @ We + be   [4096x512], K=1024, f32 A staged directly
  enc_gemm<<<dim3(DENC / 64, B_ROWS / 128, 2), 256, 0, stream>>>(
      x_img, x_txt, Wet_img, Wet_txt, be_img, be_txt, h_img, h_txt);
  // head 1: g = relu(h @ W1 + b1)   [4096x256], K=512
  gemm_glds<64, true><<<dim3(DH / 64, B_ROWS / 64, 2), 256, 0, stream>>>(
      h_img, h_txt, W1t_img, W1t_txt, b1_img, b1_txt, g_img, g_txt,
      DH, DENC);
  // head 2 + normalize fused -> fp8 reps8 directly (quant dispatch gone)
  head2_norm<<<dim3(B_ROWS / 16, 1, 2), 256, 0, stream>>>(
      g_img, g_txt, W2t_img, W2t_txt, b2_img, b2_txt, reps8);

  // sim partials via MX-fp8 K=128 MFMA
  sim_fp8_kernel<<<dim3(NSLICE, NTOT / 256), 256, 0, stream>>>(reps8, Spart);
  // per-row loss (fp8-consistent corrections), no atomics
  rowfinal_kernel<<<NTOT / 4, 256, 0, stream>>>(reps8, Spart, L);
  // mean
  reduce_kernel<<<1, 1024, 0, stream>>>(L, (float*)d_out);
}

// Round 12
// 178.988 us; speedup vs baseline: 1.0238x; 1.0238x over previous
//
#include <hip/hip_runtime.h>
#include <hip/hip_bf16.h>
#include <math.h>

typedef __bf16 bf16_t;
typedef __bf16 bf8 __attribute__((ext_vector_type(8)));
typedef __bf16 bf4 __attribute__((ext_vector_type(4)));
typedef float f32x4 __attribute__((ext_vector_type(4)));
typedef int i32x8 __attribute__((ext_vector_type(8)));
typedef unsigned char u8;

#define AS1 __attribute__((address_space(1)))
#define AS3 __attribute__((address_space(3)))

#define B_ROWS 4096
#define NTOT   8192
#define DIN    1024
#define DENC   512
#define DH     256
#define DP     128
#define NSLICE 32
#define INV_T        14.285714285714286f   // 1/0.07
#define SCALE_LOG2   20.609929155556620f   // log2(e)/0.07

__device__ __forceinline__ f32x4 mfma_16x16x32(bf8 a, bf8 b, f32x4 c) {
  return __builtin_amdgcn_mfma_f32_16x16x32_bf16(a, b, c, 0, 0, 0);
}

// ---------------------------------------------------------------------------
// prep: blocks 0..335 weight transpose [K][N] f32 -> [N][K] bf16 (LDS tiled);
// blocks 336+ x f32->bf16 cast. (R11 lesson: the bf16 x copy is HALF the
// bytes and L2/L3-resident across the encoder's 8 n-block re-reads — f32
// direct staging cost 132 MB of HBM fetch. Keep the cast.)
// ---------------------------------------------------------------------------
__global__ __launch_bounds__(256) void prep_kernel(
    const float* __restrict__ x_i, const float* __restrict__ x_t,
    const float* __restrict__ We_i, const float* __restrict__ We_t,
    const float* __restrict__ W1_i, const float* __restrict__ W1_t,
    const float* __restrict__ W2_i, const float* __restrict__ W2_t,
    bf16_t* __restrict__ xb_i, bf16_t* __restrict__ xb_t,
    bf16_t* __restrict__ Wet_i, bf16_t* __restrict__ Wet_t,
    bf16_t* __restrict__ W1t_i, bf16_t* __restrict__ W1t_t,
    bf16_t* __restrict__ W2t_i, bf16_t* __restrict__ W2t_t) {
  const int b = blockIdx.x;
  const int tid = threadIdx.x;
  if (b >= 336) {                          // ---- cast path
    int idx = (b - 336) * 256 + tid;
    const int HALF = (B_ROWS * DIN) / 4;
    const float* s; bf16_t* d; int off;
    if (idx < HALF) { s = x_i; d = xb_i; off = idx; }
    else            { s = x_t; d = xb_t; off = idx - HALF; }
    float4 v = ((const float4*)s)[off];
    bf4 w = { (bf16_t)v.x, (bf16_t)v.y, (bf16_t)v.z, (bf16_t)v.w };
    ((bf4*)d)[off] = w;
    return;
  }
  // ---- transpose path
  const float* src; bf16_t* dst; int K, N, tile;
  if (b < 128)      { src = We_i; dst = Wet_i; K = 1024; N = 512; tile = b; }
  else if (b < 256) { src = We_t; dst = Wet_t; K = 1024; N = 512; tile = b - 128; }
  else if (b < 288) { src = W1_i; dst = W1t_i; K = 512;  N = 256; tile = b - 256; }
  else if (b < 320) { src = W1_t; dst = W1t_t; K = 512;  N = 256; tile = b - 288; }
  else if (b < 328) { src = W2_i; dst = W2t_i; K = 256;  N = 128; tile = b - 320; }
  else              { src = W2_t; dst = W2t_t; K = 256;  N = 128; tile = b - 328; }
  const int tilesN = N >> 6;
  const int k0 = (tile / tilesN) * 64;
  const int n0 = (tile % tilesN) * 64;

  __shared__ float ld[64][65];
  #pragma unroll
  for (int i = 0; i < 4; ++i) {
    int cid = tid + i * 256;
    int r = cid >> 4;
    int c = (cid & 15) * 4;
    float4 v = *(const float4*)(src + (size_t)(k0 + r) * N + n0 + c);
    ld[r][c + 0] = v.x; ld[r][c + 1] = v.y; ld[r][c + 2] = v.z; ld[r][c + 3] = v.w;
  }
  __syncthreads();
  #pragma unroll
  for (int i = 0; i < 2; ++i) {
    int cid = tid + i * 256;
    int rn = cid >> 3;
    int c8 = (cid & 7) * 8;
    bf8 w;
    #pragma unroll
    for (int j = 0; j < 8; ++j) w[j] = (bf16_t)ld[c8 + j][rn];
    *(bf8*)(dst + (size_t)(n0 + rn) * K + k0 + c8) = w;
  }
}

// ---------------------------------------------------------------------------
// gemm_glds: bf16 GEMM, async global->LDS staging (width=16), double-
// buffered issue-ahead. Tile: MT x 64, BK=32. Paired img/txt via blockIdx.z.
// (R10-proven: enc ~15 us, 0 bank conflicts.)
// ---------------------------------------------------------------------------
template<int MT, bool RELU>
__global__ __launch_bounds__(256) void gemm_glds(
    const bf16_t* __restrict__ A0, const bf16_t* __restrict__ A1,
    const bf16_t* __restrict__ B0, const bf16_t* __restrict__ B1,
    const float* __restrict__ bias0, const float* __restrict__ bias1,
    bf16_t* __restrict__ out0, bf16_t* __restrict__ out1,
    int N, int K) {
  const bf16_t* A   = blockIdx.z ? A1 : A0;
  const bf16_t* Bt  = blockIdx.z ? B1 : B0;
  const float* bias = blockIdx.z ? bias1 : bias0;
  bf16_t* outp      = blockIdx.z ? out1 : out0;

  const int nb   = blockIdx.x * 64;
  const int mb   = blockIdx.y * MT;
  const int tid  = threadIdx.x;
  const int wave = tid >> 6;
  const int lane = tid & 63;
  const int l15  = lane & 15;
  const int quad = lane >> 4;
  constexpr int CH = MT / 64;

  __shared__ __align__(16) bf16_t As[2][MT * 32];
  __shared__ __align__(16) bf16_t Bs[2][64 * 32];

  f32x4 acc[CH][4];
  #pragma unroll
  for (int i = 0; i < CH; ++i)
    #pragma unroll
    for (int j = 0; j < 4; ++j) acc[i][j] = (f32x4){0.f, 0.f, 0.f, 0.f};

  auto stage = [&](int k0, int pb) {
    #pragma unroll
    for (int i = 0; i < CH; ++i) {
      const int s = tid + i * 256;
      const bf16_t* ga = A + (size_t)(mb + (s >> 2)) * K + k0 + (s & 3) * 8;
      __builtin_amdgcn_global_load_lds(
          (const AS1 void*)ga,
          (AS3 void*)(As[pb] + (size_t)(wave * 64 + i * 256) * 8), 16, 0, 0);
    }
    const bf16_t* gb = Bt + (size_t)(nb + (tid >> 2)) * K + k0 + (tid & 3) * 8;
    __builtin_amdgcn_global_load_lds(
        (const AS1 void*)gb,
        (AS3 void*)(Bs[pb] + (size_t)(wave * 64) * 8), 16, 0, 0);
  };

  stage(0, 0);
  const int T = K >> 5;
  for (int t = 0; t < T; ++t) {
    __syncthreads();
    if (t + 1 < T) stage((t + 1) << 5, (t + 1) & 1);
    const bf16_t* as = As[t & 1];
    const bf16_t* bs = Bs[t & 1];
    bf8 a[CH];
    #pragma unroll
    for (int i = 0; i < CH; ++i)
      a[i] = *(const bf8*)(as + (size_t)(wave * (16 * CH) + i * 16 + l15) * 32 + quad * 8);
    #pragma unroll
    for (int nt = 0; nt < 4; ++nt) {
      bf8 bb = *(const bf8*)(bs + (size_t)(nt * 16 + l15) * 32 + quad * 8);
      #pragma unroll
      for (int i = 0; i < CH; ++i)
        acc[i][nt] = mfma_16x16x32(a[i], bb, acc[i][nt]);
    }
  }

  #pragma unroll
  for (int i = 0; i < CH; ++i) {
    const int orow = mb + wave * (16 * CH) + i * 16 + quad * 4;
    #pragma unroll
    for (int nt = 0; nt < 4; ++nt) {
      const int ocol = nb + nt * 16 + l15;
      const float bval = bias[ocol];
      #pragma unroll
      for (int r = 0; r < 4; ++r) {
        float v = acc[i][nt][r] + bval;
        if (RELU) v = fmaxf(v, 0.f);
        outp[(size_t)(orow + r) * N + ocol] = (bf16_t)v;
      }
    }
  }
}

// ---------------------------------------------------------------------------
// head2_norm: z = g @ W2t^T + b2 (K=256, N=128) + fused L2 norm, emitting
// fp8 e4m3 reps8 DIRECTLY (RNE cvt_pk_fp8 — verified R11, absmax 0).
// 16-row blocks (512 WGs), glds-staged A+B with XOR chunk swizzle,
// double-buffered issue-ahead. Wave w covers cols w*32..w*32+31.
// ---------------------------------------------------------------------------
__global__ __launch_bounds__(256) void head2_norm(
    const bf16_t* __restrict__ A0, const bf16_t* __restrict__ A1,
    const bf16_t* __restrict__ B0, const bf16_t* __restrict__ B1,
    const float* __restrict__ bias0, const float* __restrict__ bias1,
    u8* __restrict__ reps8) {
  const bf16_t* A   = blockIdx.z ? A1 : A0;
  const bf16_t* Bt  = blockIdx.z ? B1 : B0;
  const float* bias = blockIdx.z ? bias1 : bias0;

  const int mb   = blockIdx.x * 16;
  const int tid  = threadIdx.x;
  const int wave = tid >> 6;
  const int lane = tid & 63;
  const int l15  = lane & 15;
  const int quad = lane >> 4;
  const int wc0  = wave * 32;

  __shared__ __align__(16) bf16_t Asb[2][16 * 32];
  __shared__ __align__(16) bf16_t Bsb[2][128 * 32];
  __shared__ float ssL[64];                // [wave][row]

  f32x4 acc[2];
  acc[0] = (f32x4){0.f, 0.f, 0.f, 0.f};
  acc[1] = (f32x4){0.f, 0.f, 0.f, 0.f};

  auto stage = [&](int k0, int pb) {
    if (wave == 0) {                       // A: 64 slots of 16B
      const int row = lane >> 2, j = lane & 3, cf = j ^ (row & 3);
      const bf16_t* ga = A + (size_t)(mb + row) * DH + k0 + cf * 8;
      __builtin_amdgcn_global_load_lds(
          (const AS1 void*)ga, (AS3 void*)(Asb[pb]), 16, 0, 0);
    }
    #pragma unroll
    for (int i = 0; i < 2; ++i) {          // B: 512 slots of 16B
      const int s = wave * 64 + i * 256 + lane;
      const int col = s >> 2, j = s & 3, cf = j ^ (col & 3);
      const bf16_t* gb = Bt + (size_t)col * DH + k0 + cf * 8;
      __builtin_amdgcn_global_load_lds(
          (const AS1 void*)gb,
          (AS3 void*)(Bsb[pb] + (size_t)(wave * 64 + i * 256) * 8), 16, 0, 0);
    }
  };

  stage(0, 0);
  for (int t = 0; t < 8; ++t) {
    __syncthreads();
    if (t < 7) stage((t + 1) << 5, (t + 1) & 1);
    const bf16_t* as = Asb[t & 1];
    const bf16_t* bs = Bsb[t & 1];
    bf8 a = *(const bf8*)(as + (size_t)(l15 * 4 + (quad ^ (l15 & 3))) * 8);
    #pragma unroll
    for (int nt = 0; nt < 2; ++nt) {
      const int col = wc0 + nt * 16 + l15;
      bf8 bb = *(const bf8*)(bs + (size_t)(col * 4 + (quad ^ (col & 3))) * 8);
      acc[nt] = mfma_16x16x32(a, bb, acc[nt]);
    }
  }

  float ssp[4];
  #pragma unroll
  for (int r = 0; r < 4; ++r) {
    #pragma unroll
    for (int nt = 0; nt < 2; ++nt) acc[nt][r] += bias[wc0 + nt * 16 + l15];
    float s = acc[0][r] * acc[0][r] + acc[1][r] * acc[1][r];
    s += __shfl_xor(s, 1); s += __shfl_xor(s, 2);
    s += __shfl_xor(s, 4); s += __shfl_xor(s, 8);
    ssp[r] = s;
  }
  if (l15 == 0) {
    #pragma unroll
    for (int r = 0; r < 4; ++r) ssL[wave * 16 + quad * 4 + r] = ssp[r];
  }
  __syncthreads();
  const size_t gr0 = (size_t)(blockIdx.z ? B_ROWS : 0) + mb + quad * 4;
  #pragma unroll
  for (int r = 0; r < 4; ++r) {
    const int row = quad * 4 + r;
    float tot = ssL[row] + ssL[16 + row] + ssL[32 + row] + ssL[48 + row];
    const float inv = 1.0f / fmaxf(sqrtf(tot), 1e-12f);
    int pk = __builtin_amdgcn_cvt_pk_fp8_f32(acc[0][r] * inv, acc[1][r] * inv, 0, 0);
    reps8[(gr0 + r) * DP + wc0 + l15]      = (u8)(pk & 0xff);
    reps8[(gr0 + r) * DP + wc0 + 16 + l15] = (u8)((pk >> 8) & 0xff);
  }
}

// ---------------------------------------------------------------------------
// sim_fp8: fused reps8·reps8ᵀ + exp row-sums via MX-scaled fp8 MFMA
// (16x16x128, scales 1.0). 2-barrier LDS staging, 8 KB tiles, XOR swizzle.
// WG = 256 rows x 256-col slice, grid (32,32)=1024. Private Spart slots.
// ---------------------------------------------------------------------------
__global__ __launch_bounds__(256) void sim_fp8_kernel(
    const u8* __restrict__ reps8, float* __restrict__ Spart) {
  const int rowbase = blockIdx.y * 256;
  const int slice   = blockIdx.x;
  const int col0    = slice * 256;
  const int tid  = threadIdx.x;
  const int wave = tid >> 6;
  const int lane = tid & 63;
  const int l15  = lane & 15;
  const int quad = lane >> 4;

  __shared__ __align__(16) u8 Bs[2][64 * DP];   // 2 x 8 KB

  const int r0 = rowbase + wave * 64;
  i32x8 af[4];
  #pragma unroll
  for (int c = 0; c < 4; ++c) {
    const uint4* ap = (const uint4*)(reps8 + (size_t)(r0 + c * 16 + l15) * DP + quad * 32);
    uint4 x0 = ap[0], x1 = ap[1];
    af[c] = (i32x8){(int)x0.x, (int)x0.y, (int)x0.z, (int)x0.w,
                    (int)x1.x, (int)x1.y, (int)x1.z, (int)x1.w};
  }

  float rs[4][4];
  #pragma unroll
  for (int c = 0; c < 4; ++c)
    #pragma unroll
    for (int r = 0; r < 4; ++r) rs[c][r] = 0.f;

  for (int t = 0; t < 4; ++t) {
    u8* buf = Bs[t & 1];
    __syncthreads();
    const int jt0 = col0 + t * 64;
    #pragma unroll
    for (int i = 0; i < 2; ++i) {          // stage 8 KB: 512 slots of 16B
      const int s   = i * 256 + tid;
      const int col = s >> 3;
      const int cf  = (s & 7) ^ (col & 7);
      const u8* g = reps8 + (size_t)(jt0 + col) * DP + cf * 16;
      __builtin_amdgcn_global_load_lds(
          (const AS1 void*)g,
          (AS3 void*)(buf + (size_t)(i * 256 + wave * 64) * 16), 16, 0, 0);
    }
    __syncthreads();

    #pragma unroll
    for (int st = 0; st < 4; ++st) {
      const int coln = st * 16 + l15;
      const u8* cbase = buf + (size_t)coln * DP;
      const int c0 = ((2 * quad)     ^ (coln & 7)) * 16;
      const int c1 = ((2 * quad + 1) ^ (coln & 7)) * 16;
      uint4 b0 = *(const uint4*)(cbase + c0);
      uint4 b1 = *(const uint4*)(cbase + c1);
      i32x8 bf = (i32x8){(int)b0.x, (int)b0.y, (int)b0.z, (int)b0.w,
                         (int)b1.x, (int)b1.y, (int)b1.z, (int)b1.w};
      #pragma unroll
      for (int c = 0; c < 4; ++c) {
        f32x4 acc = (f32x4){0.f, 0.f, 0.f, 0.f};
        acc = __builtin_amdgcn_mfma_scale_f32_16x16x128_f8f6f4(
            af[c], bf, acc, 0, 0, 0, 0x7F7F7F7F, 0, 0x7F7F7F7F);
        #pragma unroll
        for (int r = 0; r < 4; ++r)
          rs[c][r] += __builtin_amdgcn_exp2f(acc[r] * SCALE_LOG2);
      }
    }
  }

  #pragma unroll
  for (int c = 0; c < 4; ++c) {
    const int i0 = r0 + c * 16 + quad * 4;
    #pragma unroll
    for (int r = 0; r < 4; ++r) {
      float v = rs[c][r];
      v += __shfl_xor(v, 1); v += __shfl_xor(v, 2);
      v += __shfl_xor(v, 4); v += __shfl_xor(v, 8);
      if (l15 == 0) Spart[(size_t)slice * NTOT + i0 + r] = v;
    }
  }
}

// ---------------------------------------------------------------------------
// rowfinal: one wave per row, no atomics/fences. dii/pos computed from the
// SAME fp8 values the MFMA consumed -> dominant e^{dii/t} cancels cleanly.
//   L_i = log(sum(parts) - exp(dii/t) + exp(pos/t)) - pos/t
// ---------------------------------------------------------------------------
__global__ __launch_bounds__(256) void rowfinal_kernel(
    const u8* __restrict__ reps8, const float* __restrict__ Spart,
    float* __restrict__ L) {
  const int tid  = threadIdx.x;
  const int wave = tid >> 6;
  const int lane = tid & 63;
  const int row  = blockIdx.x * 4 + wave;
  const int ua = *(const unsigned short*)(reps8 + (size_t)row * DP + lane * 2);
  const int ub = *(const unsigned short*)(reps8 + (size_t)(row ^ B_ROWS) * DP + lane * 2);
  float a0 = __builtin_amdgcn_cvt_f32_fp8(ua, 0);
  float a1 = __builtin_amdgcn_cvt_f32_fp8(ua, 1);
  float b0 = __builtin_amdgcn_cvt_f32_fp8(ub, 0);
  float b1 = __builtin_amdgcn_cvt_f32_fp8(ub, 1);
  float dii = a0 * a0 + a1 * a1;
  float pos = a0 * b0 + a1 * b1;
  float ps  = (lane < NSLICE) ? Spart[(size_t)lane * NTOT + row] : 0.f;
  #pragma unroll
  for (int m = 1; m < 64; m <<= 1) {
    dii += __shfl_xor(dii, m);
    pos += __shfl_xor(pos, m);
    ps  += __shfl_xor(ps, m);
  }
  if (lane == 0) {
    float Si = ps - __builtin_amdgcn_exp2f(dii * SCALE_LOG2)
                  + __builtin_amdgcn_exp2f(pos * SCALE_LOG2);
    L[row] = logf(Si) - pos * INV_T;
  }
}

// ---------------------------------------------------------------------------
// reduce: mean over 8192 per-row losses -> d_out[0]. Single block.
// ---------------------------------------------------------------------------
__global__ __launch_bounds__(1024) void reduce_kernel(
    const float* __restrict__ L, float* __restrict__ out) {
  const int tid = threadIdx.x;
  float acc = 0.f;
  for (int i = tid; i < NTOT; i += 1024) acc += L[i];
  #pragma unroll
  for (int m = 1; m < 64; m <<= 1) acc += __shfl_xor(acc, m);
  __shared__ float wsum[16];
  if ((tid & 63) == 0) wsum[tid >> 6] = acc;
  __syncthreads();
  if (tid < 16) {
    float v = wsum[tid];
    #pragma unroll
    for (int m = 1; m < 16; m <<= 1) v += __shfl_xor(v, m);
    if (tid == 0) out[0] = v * (1.0f / NTOT);
  }
}

// ---------------------------------------------------------------------------
extern "C" void kernel_launch(void* const* d_in, const int* in_sizes, int n_in,
                              void* d_out, int out_size, void* d_ws, size_t ws_size,
                              hipStream_t stream) {
  const float* x_img  = (const float*)d_in[0];
  const float* x_txt  = (const float*)d_in[1];
  const float* We_img = (const float*)d_in[2];
  const float* be_img = (const float*)d_in[3];
  const float* We_txt = (const float*)d_in[4];
  const float* be_txt = (const float*)d_in[5];
  const float* W1_img = (const float*)d_in[6];
  const float* b1_img = (const float*)d_in[7];
  const float* W2_img = (const float*)d_in[8];
  const float* b2_img = (const float*)d_in[9];
  const float* W1_txt = (const float*)d_in[10];
  const float* b1_txt = (const float*)d_in[11];
  const float* W2_txt = (const float*)d_in[12];
  const float* b2_txt = (const float*)d_in[13];

  char* p = (char*)d_ws;
  bf16_t* xbf_img = (bf16_t*)p; p += (size_t)B_ROWS * DIN * 2;
  bf16_t* xbf_txt = (bf16_t*)p; p += (size_t)B_ROWS * DIN * 2;
  bf16_t* Wet_img = (bf16_t*)p; p += (size_t)DENC * DIN * 2;
  bf16_t* Wet_txt = (bf16_t*)p; p += (size_t)DENC * DIN * 2;
  bf16_t* W1t_img = (bf16_t*)p; p += (size_t)DH * DENC * 2;
  bf16_t* W1t_txt = (bf16_t*)p; p += (size_t)DH * DENC * 2;
  bf16_t* W2t_img = (bf16_t*)p; p += (size_t)DP * DH * 2;
  bf16_t* W2t_txt = (bf16_t*)p; p += (size_t)DP * DH * 2;
  bf16_t* h_img   = (bf16_t*)p; p += (size_t)B_ROWS * DENC * 2;
  bf16_t* h_txt   = (bf16_t*)p; p += (size_t)B_ROWS * DENC * 2;
  bf16_t* g_img   = (bf16_t*)p; p += (size_t)B_ROWS * DH * 2;
  bf16_t* g_txt   = (bf16_t*)p; p += (size_t)B_ROWS * DH * 2;
  u8*     reps8   = (u8*)    p; p += (size_t)NTOT * DP;
  float*  Spart   = (float*) p; p += (size_t)NSLICE * NTOT * 4;
  float*  L       = (float*) p; p += (size_t)NTOT * 4;

  prep_kernel<<<336 + 8192, 256, 0, stream>>>(
      x_img, x_txt, We_img, We_txt, W1_img, W1_txt, W2_img, W2_txt,
      xbf_img, xbf_txt, Wet_img, Wet_txt, W1t_img, W1t_txt, W2t_img, W2t_txt);

  // encoder: h = x @ We + be   [4096x512], K=1024 (bf16 A, R10-proven)
  gemm_glds<128, false><<<dim3(DENC / 64, B_ROWS / 128, 2), 256, 0, stream>>>(
      xbf_img, xbf_txt, Wet_img, Wet_txt, be_img, be_txt, h_img, h_txt,
      DENC, DIN);
  // head 1: g = relu(h @ W1 + b1)   [4096x256], K=512
  gemm_glds<64, true><<<dim3(DH / 64, B_ROWS / 64, 2), 256, 0, stream>>>(
      h_img, h_txt, W1t_img, W1t_txt, b1_img, b1_txt, g_img, g_txt,
      DH, DENC);
  // head 2 + normalize fused -> fp8 reps8 directly
  head2_norm<<<dim3(B_ROWS / 16, 1, 2), 256, 0, stream>>>(
      g_img, g_txt, W2t_img, W2t_txt, b2_img, b2_txt, reps8);

  // sim partials via MX-fp8 K=128 MFMA
  sim_fp8_kernel<<<dim3(NSLICE, NTOT / 256), 256, 0, stream>>>(reps8, Spart);
  // per-row loss (fp8-consistent corrections), no atomics
  rowfinal_kernel<<<NTOT / 4, 256, 0, stream>>>(reps8, Spart, L);
  // mean
  reduce_kernel<<<1, 1024, 0, stream>>>(L, (float*)d_out);
}

// Round 13
// 178.763 us; speedup vs baseline: 1.0251x; 1.0013x over previous
//
#include <hip/hip_runtime.h>
#include <hip/hip_bf16.h>
#include <math.h>

typedef __bf16 bf16_t;
typedef __bf16 bf8 __attribute__((ext_vector_type(8)));
typedef __bf16 bf4 __attribute__((ext_vector_type(4)));
typedef float f32x4 __attribute__((ext_vector_type(4)));
typedef int i32x8 __attribute__((ext_vector_type(8)));
typedef unsigned char u8;

#define AS1 __attribute__((address_space(1)))
#define AS3 __attribute__((address_space(3)))

#define B_ROWS 4096
#define NTOT   8192
#define DIN    1024
#define DENC   512
#define DH     256
#define DP     128
#define NSLICE 32
#define INV_T        14.285714285714286f   // 1/0.07
#define SCALE_LOG2   20.609929155556620f   // log2(e)/0.07

__device__ __forceinline__ f32x4 mfma_16x16x32(bf8 a, bf8 b, f32x4 c) {
  return __builtin_amdgcn_mfma_f32_16x16x32_bf16(a, b, c, 0, 0, 0);
}

// ---------------------------------------------------------------------------
// prep: blocks 0..335 weight transpose [K][N] f32 -> [N][K] bf16 (LDS tiled);
// blocks 336+ x f32->bf16 cast. (R11 lesson: the bf16 x copy is HALF the
// bytes and L2/L3-resident across the encoder's 8 n-block re-reads — f32
// direct staging cost 132 MB of HBM fetch. Keep the cast.)
// ---------------------------------------------------------------------------
__global__ __launch_bounds__(256) void prep_kernel(
    const float* __restrict__ x_i, const float* __restrict__ x_t,
    const float* __restrict__ We_i, const float* __restrict__ We_t,
    const float* __restrict__ W1_i, const float* __restrict__ W1_t,
    const float* __restrict__ W2_i, const float* __restrict__ W2_t,
    bf16_t* __restrict__ xb_i, bf16_t* __restrict__ xb_t,
    bf16_t* __restrict__ Wet_i, bf16_t* __restrict__ Wet_t,
    bf16_t* __restrict__ W1t_i, bf16_t* __restrict__ W1t_t,
    bf16_t* __restrict__ W2t_i, bf16_t* __restrict__ W2t_t) {
  const int b = blockIdx.x;
  const int tid = threadIdx.x;
  if (b >= 336) {                          // ---- cast path
    int idx = (b - 336) * 256 + tid;
    const int HALF = (B_ROWS * DIN) / 4;
    const float* s; bf16_t* d; int off;
    if (idx < HALF) { s = x_i; d = xb_i; off = idx; }
    else            { s = x_t; d = xb_t; off = idx - HALF; }
    float4 v = ((const float4*)s)[off];
    bf4 w = { (bf16_t)v.x, (bf16_t)v.y, (bf16_t)v.z, (bf16_t)v.w };
    ((bf4*)d)[off] = w;
    return;
  }
  // ---- transpose path
  const float* src; bf16_t* dst; int K, N, tile;
  if (b < 128)      { src = We_i; dst = Wet_i; K = 1024; N = 512; tile = b; }
  else if (b < 256) { src = We_t; dst = Wet_t; K = 1024; N = 512; tile = b - 128; }
  else if (b < 288) { src = W1_i; dst = W1t_i; K = 512;  N = 256; tile = b - 256; }
  else if (b < 320) { src = W1_t; dst = W1t_t; K = 512;  N = 256; tile = b - 288; }
  else if (b < 328) { src = W2_i; dst = W2t_i; K = 256;  N = 128; tile = b - 320; }
  else              { src = W2_t; dst = W2t_t; K = 256;  N = 128; tile = b - 328; }
  const int tilesN = N >> 6;
  const int k0 = (tile / tilesN) * 64;
  const int n0 = (tile % tilesN) * 64;

  __shared__ float ld[64][65];
  #pragma unroll
  for (int i = 0; i < 4; ++i) {
    int cid = tid + i * 256;
    int r = cid >> 4;
    int c = (cid & 15) * 4;
    float4 v = *(const float4*)(src + (size_t)(k0 + r) * N + n0 + c);
    ld[r][c + 0] = v.x; ld[r][c + 1] = v.y; ld[r][c + 2] = v.z; ld[r][c + 3] = v.w;
  }
  __syncthreads();
  #pragma unroll
  for (int i = 0; i < 2; ++i) {
    int cid = tid + i * 256;
    int rn = cid >> 3;
    int c8 = (cid & 7) * 8;
    bf8 w;
    #pragma unroll
    for (int j = 0; j < 8; ++j) w[j] = (bf16_t)ld[c8 + j][rn];
    *(bf8*)(dst + (size_t)(n0 + rn) * K + k0 + c8) = w;
  }
}

// ---------------------------------------------------------------------------
// gemm_glds: bf16 GEMM, async global->LDS staging (width=16), double-
// buffered issue-ahead. Tile: MT x 64, BK=32. Paired img/txt via blockIdx.z.
// (R10-proven: enc ~15 us, 0 bank conflicts.)
// ---------------------------------------------------------------------------
template<int MT, bool RELU>
__global__ __launch_bounds__(256) void gemm_glds(
    const bf16_t* __restrict__ A0, const bf16_t* __restrict__ A1,
    const bf16_t* __restrict__ B0, const bf16_t* __restrict__ B1,
    const float* __restrict__ bias0, const float* __restrict__ bias1,
    bf16_t* __restrict__ out0, bf16_t* __restrict__ out1,
    int N, int K) {
  const bf16_t* A   = blockIdx.z ? A1 : A0;
  const bf16_t* Bt  = blockIdx.z ? B1 : B0;
  const float* bias = blockIdx.z ? bias1 : bias0;
  bf16_t* outp      = blockIdx.z ? out1 : out0;

  const int nb   = blockIdx.x * 64;
  const int mb   = blockIdx.y * MT;
  const int tid  = threadIdx.x;
  const int wave = tid >> 6;
  const int lane = tid & 63;
  const int l15  = lane & 15;
  const int quad = lane >> 4;
  constexpr int CH = MT / 64;

  __shared__ __align__(16) bf16_t As[2][MT * 32];
  __shared__ __align__(16) bf16_t Bs[2][64 * 32];

  f32x4 acc[CH][4];
  #pragma unroll
  for (int i = 0; i < CH; ++i)
    #pragma unroll
    for (int j = 0; j < 4; ++j) acc[i][j] = (f32x4){0.f, 0.f, 0.f, 0.f};

  auto stage = [&](int k0, int pb) {
    #pragma unroll
    for (int i = 0; i < CH; ++i) {
      const int s = tid + i * 256;
      const bf16_t* ga = A + (size_t)(mb + (s >> 2)) * K + k0 + (s & 3) * 8;
      __builtin_amdgcn_global_load_lds(
          (const AS1 void*)ga,
          (AS3 void*)(As[pb] + (size_t)(wave * 64 + i * 256) * 8), 16, 0, 0);
    }
    const bf16_t* gb = Bt + (size_t)(nb + (tid >> 2)) * K + k0 + (tid & 3) * 8;
    __builtin_amdgcn_global_load_lds(
        (const AS1 void*)gb,
        (AS3 void*)(Bs[pb] + (size_t)(wave * 64) * 8), 16, 0, 0);
  };

  stage(0, 0);
  const int T = K >> 5;
  for (int t = 0; t < T; ++t) {
    __syncthreads();
    if (t + 1 < T) stage((t + 1) << 5, (t + 1) & 1);
    const bf16_t* as = As[t & 1];
    const bf16_t* bs = Bs[t & 1];
    bf8 a[CH];
    #pragma unroll
    for (int i = 0; i < CH; ++i)
      a[i] = *(const bf8*)(as + (size_t)(wave * (16 * CH) + i * 16 + l15) * 32 + quad * 8);
    #pragma unroll
    for (int nt = 0; nt < 4; ++nt) {
      bf8 bb = *(const bf8*)(bs + (size_t)(nt * 16 + l15) * 32 + quad * 8);
      #pragma unroll
      for (int i = 0; i < CH; ++i)
        acc[i][nt] = mfma_16x16x32(a[i], bb, acc[i][nt]);
    }
  }

  #pragma unroll
  for (int i = 0; i < CH; ++i) {
    const int orow = mb + wave * (16 * CH) + i * 16 + quad * 4;
    #pragma unroll
    for (int nt = 0; nt < 4; ++nt) {
      const int ocol = nb + nt * 16 + l15;
      const float bval = bias[ocol];
      #pragma unroll
      for (int r = 0; r < 4; ++r) {
        float v = acc[i][nt][r] + bval;
        if (RELU) v = fmaxf(v, 0.f);
        outp[(size_t)(orow + r) * N + ocol] = (bf16_t)v;
      }
    }
  }
}

// ---------------------------------------------------------------------------
// head2_norm: z = g @ W2t^T + b2 (K=256, N=128) + fused L2 norm, emitting
// fp8 e4m3 reps8 DIRECTLY (RNE cvt_pk_fp8 — verified R11, absmax 0).
// 16-row blocks (512 WGs), glds-staged A+B with XOR chunk swizzle,
// double-buffered issue-ahead. Wave w covers cols w*32..w*32+31.
// ---------------------------------------------------------------------------
__global__ __launch_bounds__(256) void head2_norm(
    const bf16_t* __restrict__ A0, const bf16_t* __restrict__ A1,
    const bf16_t* __restrict__ B0, const bf16_t* __restrict__ B1,
    const float* __restrict__ bias0, const float* __restrict__ bias1,
    u8* __restrict__ reps8) {
  const bf16_t* A   = blockIdx.z ? A1 : A0;
  const bf16_t* Bt  = blockIdx.z ? B1 : B0;
  const float* bias = blockIdx.z ? bias1 : bias0;

  const int mb   = blockIdx.x * 16;
  const int tid  = threadIdx.x;
  const int wave = tid >> 6;
  const int lane = tid & 63;
  const int l15  = lane & 15;
  const int quad = lane >> 4;
  const int wc0  = wave * 32;

  __shared__ __align__(16) bf16_t Asb[2][16 * 32];
  __shared__ __align__(16) bf16_t Bsb[2][128 * 32];
  __shared__ float ssL[64];                // [wave][row]

  f32x4 acc[2];
  acc[0] = (f32x4){0.f, 0.f, 0.f, 0.f};
  acc[1] = (f32x4){0.f, 0.f, 0.f, 0.f};

  auto stage = [&](int k0, int pb) {
    if (wave == 0) {                       // A: 64 slots of 16B
      const int row = lane >> 2, j = lane & 3, cf = j ^ (row & 3);
      const bf16_t* ga = A + (size_t)(mb + row) * DH + k0 + cf * 8;
      __builtin_amdgcn_global_load_lds(
          (const AS1 void*)ga, (AS3 void*)(Asb[pb]), 16, 0, 0);
    }
    #pragma unroll
    for (int i = 0; i < 2; ++i) {          // B: 512 slots of 16B
      const int s = wave * 64 + i * 256 + lane;
      const int col = s >> 2, j = s & 3, cf = j ^ (col & 3);
      const bf16_t* gb = Bt + (size_t)col * DH + k0 + cf * 8;
      __builtin_amdgcn_global_load_lds(
          (const AS1 void*)gb,
          (AS3 void*)(Bsb[pb] + (size_t)(wave * 64 + i * 256) * 8), 16, 0, 0);
    }
  };

  stage(0, 0);
  for (int t = 0; t < 8; ++t) {
    __syncthreads();
    if (t < 7) stage((t + 1) << 5, (t + 1) & 1);
    const bf16_t* as = Asb[t & 1];
    const bf16_t* bs = Bsb[t & 1];
    bf8 a = *(const bf8*)(as + (size_t)(l15 * 4 + (quad ^ (l15 & 3))) * 8);
    #pragma unroll
    for (int nt = 0; nt < 2; ++nt) {
      const int col = wc0 + nt * 16 + l15;
      bf8 bb = *(const bf8*)(bs + (size_t)(col * 4 + (quad ^ (col & 3))) * 8);
      acc[nt] = mfma_16x16x32(a, bb, acc[nt]);
    }
  }

  float ssp[4];
  #pragma unroll
  for (int r = 0; r < 4; ++r) {
    #pragma unroll
    for (int nt = 0; nt < 2; ++nt) acc[nt][r] += bias[wc0 + nt * 16 + l15];
    float s = acc[0][r] * acc[0][r] + acc[1][r] * acc[1][r];
    s += __shfl_xor(s, 1); s += __shfl_xor(s, 2);
    s += __shfl_xor(s, 4); s += __shfl_xor(s, 8);
    ssp[r] = s;
  }
  if (l15 == 0) {
    #pragma unroll
    for (int r = 0; r < 4; ++r) ssL[wave * 16 + quad * 4 + r] = ssp[r];
  }
  __syncthreads();
  const size_t gr0 = (size_t)(blockIdx.z ? B_ROWS : 0) + mb + quad * 4;
  #pragma unroll
  for (int r = 0; r < 4; ++r) {
    const int row = quad * 4 + r;
    float tot = ssL[row] + ssL[16 + row] + ssL[32 + row] + ssL[48 + row];
    const float inv = 1.0f / fmaxf(sqrtf(tot), 1e-12f);
    int pk = __builtin_amdgcn_cvt_pk_fp8_f32(acc[0][r] * inv, acc[1][r] * inv, 0, 0);
    reps8[(gr0 + r) * DP + wc0 + l15]      = (u8)(pk & 0xff);
    reps8[(gr0 + r) * DP + wc0 + 16 + l15] = (u8)((pk >> 8) & 0xff);
  }
}

// ---------------------------------------------------------------------------
// sim_fp8: fused reps8·reps8ᵀ + exp row-sums via MX-scaled fp8 MFMA
// (16x16x128, scales 1.0). NOW with issue-ahead double-buffering: stage(t+1)
// into the opposite 8 KB buffer BEFORE compute(t) — one barrier per tile,
// the glds fetch overlaps the ~700 cyc of MFMA+exp (the R7 scare was the
// correction tail, not issue-ahead; gemm_glds has run this shape since R5).
// WG = 256 rows x 256-col slice, grid (32,32)=1024. Private Spart slots,
// no atomics/fences. XOR chunk swizzle: glds lane-contiguous+conflict-free.
// ---------------------------------------------------------------------------
__global__ __launch_bounds__(256) void sim_fp8_kernel(
    const u8* __restrict__ reps8, float* __restrict__ Spart) {
  const int rowbase = blockIdx.y * 256;
  const int slice   = blockIdx.x;
  const int col0    = slice * 256;
  const int tid  = threadIdx.x;
  const int wave = tid >> 6;
  const int lane = tid & 63;
  const int l15  = lane & 15;
  const int quad = lane >> 4;

  __shared__ __align__(16) u8 Bs[2][64 * DP];   // 2 x 8 KB

  const int r0 = rowbase + wave * 64;
  i32x8 af[4];
  #pragma unroll
  for (int c = 0; c < 4; ++c) {
    const uint4* ap = (const uint4*)(reps8 + (size_t)(r0 + c * 16 + l15) * DP + quad * 32);
    uint4 x0 = ap[0], x1 = ap[1];
    af[c] = (i32x8){(int)x0.x, (int)x0.y, (int)x0.z, (int)x0.w,
                    (int)x1.x, (int)x1.y, (int)x1.z, (int)x1.w};
  }

  float rs[4][4];
  #pragma unroll
  for (int c = 0; c < 4; ++c)
    #pragma unroll
    for (int r = 0; r < 4; ++r) rs[c][r] = 0.f;

  auto stage = [&](int t, int pb) {
    const int jt0 = col0 + t * 64;
    #pragma unroll
    for (int i = 0; i < 2; ++i) {          // stage 8 KB: 512 slots of 16B
      const int s   = i * 256 + tid;
      const int col = s >> 3;
      const int cf  = (s & 7) ^ (col & 7);
      const u8* g = reps8 + (size_t)(jt0 + col) * DP + cf * 16;
      __builtin_amdgcn_global_load_lds(
          (const AS1 void*)g,
          (AS3 void*)(Bs[pb] + (size_t)(i * 256 + wave * 64) * 16), 16, 0, 0);
    }
  };

  stage(0, 0);
  for (int t = 0; t < 4; ++t) {
    __syncthreads();                       // tile t visible; compute(t-1) done
    if (t + 1 < 4) stage(t + 1, (t + 1) & 1);
    const u8* buf = Bs[t & 1];

    #pragma unroll
    for (int st = 0; st < 4; ++st) {
      const int coln = st * 16 + l15;
      const u8* cbase = buf + (size_t)coln * DP;
      const int c0 = ((2 * quad)     ^ (coln & 7)) * 16;
      const int c1 = ((2 * quad + 1) ^ (coln & 7)) * 16;
      uint4 b0 = *(const uint4*)(cbase + c0);
      uint4 b1 = *(const uint4*)(cbase + c1);
      i32x8 bf = (i32x8){(int)b0.x, (int)b0.y, (int)b0.z, (int)b0.w,
                         (int)b1.x, (int)b1.y, (int)b1.z, (int)b1.w};
      #pragma unroll
      for (int c = 0; c < 4; ++c) {
        f32x4 acc = (f32x4){0.f, 0.f, 0.f, 0.f};
        acc = __builtin_amdgcn_mfma_scale_f32_16x16x128_f8f6f4(
            af[c], bf, acc, 0, 0, 0, 0x7F7F7F7F, 0, 0x7F7F7F7F);
        #pragma unroll
        for (int r = 0; r < 4; ++r)
          rs[c][r] += __builtin_amdgcn_exp2f(acc[r] * SCALE_LOG2);
      }
    }
  }

  #pragma unroll
  for (int c = 0; c < 4; ++c) {
    const int i0 = r0 + c * 16 + quad * 4;
    #pragma unroll
    for (int r = 0; r < 4; ++r) {
      float v = rs[c][r];
      v += __shfl_xor(v, 1); v += __shfl_xor(v, 2);
      v += __shfl_xor(v, 4); v += __shfl_xor(v, 8);
      if (l15 == 0) Spart[(size_t)slice * NTOT + i0 + r] = v;
    }
  }
}

// ---------------------------------------------------------------------------
// rowfinal: one wave per row, no atomics/fences. dii/pos computed from the
// SAME fp8 values the MFMA consumed -> dominant e^{dii/t} cancels cleanly.
//   L_i = log(sum(parts) - exp(dii/t) + exp(pos/t)) - pos/t
// ---------------------------------------------------------------------------
__global__ __launch_bounds__(256) void rowfinal_kernel(
    const u8* __restrict__ reps8, const float* __restrict__ Spart,
    float* __restrict__ L) {
  const int tid  = threadIdx.x;
  const int wave = tid >> 6;
  const int lane = tid & 63;
  const int row  = blockIdx.x * 4 + wave;
  const int ua = *(const unsigned short*)(reps8 + (size_t)row * DP + lane * 2);
  const int ub = *(const unsigned short*)(reps8 + (size_t)(row ^ B_ROWS) * DP + lane * 2);
  float a0 = __builtin_amdgcn_cvt_f32_fp8(ua, 0);
  float a1 = __builtin_amdgcn_cvt_f32_fp8(ua, 1);
  float b0 = __builtin_amdgcn_cvt_f32_fp8(ub, 0);
  float b1 = __builtin_amdgcn_cvt_f32_fp8(ub, 1);
  float dii = a0 * a0 + a1 * a1;
  float pos = a0 * b0 + a1 * b1;
  float ps  = (lane < NSLICE) ? Spart[(size_t)lane * NTOT + row] : 0.f;
  #pragma unroll
  for (int m = 1; m < 64; m <<= 1) {
    dii += __shfl_xor(dii, m);
    pos += __shfl_xor(pos, m);
    ps  += __shfl_xor(ps, m);
  }
  if (lane == 0) {
    float Si = ps - __builtin_amdgcn_exp2f(dii * SCALE_LOG2)
                  + __builtin_amdgcn_exp2f(pos * SCALE_LOG2);
    L[row] = logf(Si) - pos * INV_T;
  }
}

// ---------------------------------------------------------------------------
// reduce: mean over 8192 per-row losses -> d_out[0]. Single block.
// ---------------------------------------------------------------------------
__global__ __launch_bounds__(1024) void reduce_kernel(
    const float* __restrict__ L, float* __restrict__ out) {
  const int tid = threadIdx.x;
  float acc = 0.f;
  for (int i = tid; i < NTOT; i += 1024) acc += L[i];
  #pragma unroll
  for (int m = 1; m < 64; m <<= 1) acc += __shfl_xor(acc, m);
  __shared__ float wsum[16];
  if ((tid & 63) == 0) wsum[tid >> 6] = acc;
  __syncthreads();
  if (tid < 16) {
    float v = wsum[tid];
    #pragma unroll
    for (int m = 1; m < 16; m <<= 1) v += __shfl_xor(v, m);
    if (tid == 0) out[0] = v * (1.0f / NTOT);
  }
}

// ---------------------------------------------------------------------------
extern "C" void kernel_launch(void* const* d_in, const int* in_sizes, int n_in,
                              void* d_out, int out_size, void* d_ws, size_t ws_size,
                              hipStream_t stream) {
  const float* x_img  = (const float*)d_in[0];
  const float* x_txt  = (const float*)d_in[1];
  const float* We_img = (const float*)d_in[2];
  const float* be_img = (const float*)d_in[3];
  const float* We_txt = (const float*)d_in[4];
  const float* be_txt = (const float*)d_in[5];
  const float* W1_img = (const float*)d_in[6];
  const float* b1_img = (const float*)d_in[7];
  const float* W2_img = (const float*)d_in[8];
  const float* b2_img = (const float*)d_in[9];
  const float* W1_txt = (const float*)d_in[10];
  const float* b1_txt = (const float*)d_in[11];
  const float* W2_txt = (const float*)d_in[12];
  const float* b2_txt = (const float*)d_in[13];

  char* p = (char*)d_ws;
  bf16_t* xbf_img = (bf16_t*)p; p += (size_t)B_ROWS * DIN * 2;
  bf16_t* xbf_txt = (bf16_t*)p; p += (size_t)B_ROWS * DIN * 2;
  bf16_t* Wet_img = (bf16_t*)p; p += (size_t)DENC * DIN * 2;
  bf16_t* Wet_txt = (bf16_t*)p; p += (size_t)DENC * DIN * 2;
  bf16_t* W1t_img = (bf16_t*)p; p += (size_t)DH * DENC * 2;
  bf16_t* W1t_txt = (bf16_t*)p; p += (size_t)DH * DENC * 2;
  bf16_t* W2t_img = (bf16_t*)p; p += (size_t)DP * DH * 2;
  bf16_t* W2t_txt = (bf16_t*)p; p += (size_t)DP * DH * 2;
  bf16_t* h_img   = (bf16_t*)p; p += (size_t)B_ROWS * DENC * 2;
  bf16_t* h_txt   = (bf16_t*)p; p += (size_t)B_ROWS * DENC * 2;
  bf16_t* g_img   = (bf16_t*)p; p += (size_t)B_ROWS * DH * 2;
  bf16_t* g_txt   = (bf16_t*)p; p += (size_t)B_ROWS * DH * 2;
  u8*     reps8   = (u8*)    p; p += (size_t)NTOT * DP;
  float*  Spart   = (float*) p; p += (size_t)NSLICE * NTOT * 4;
  float*  L       = (float*) p; p += (size_t)NTOT * 4;

  prep_kernel<<<336 + 8192, 256, 0, stream>>>(
      x_img, x_txt, We_img, We_txt, W1_img, W1_txt, W2_img, W2_txt,
      xbf_img, xbf_txt, Wet_img, Wet_txt, W1t_img, W1t_txt, W2t_img, W2t_txt);

  // encoder: h = x @ We + be   [4096x512], K=1024 (bf16 A, R10-proven)
  gemm_glds<128, false><<<dim3(DENC / 64, B_ROWS / 128, 2), 256, 0, stream>>>(
      xbf_img, xbf_txt, Wet_img, Wet_txt, be_img, be_txt, h_img, h_txt,
      DENC, DIN);
  // head 1: g = relu(h @ W1 + b1)   [4096x256], K=512
  gemm_glds<64, true><<<dim3(DH / 64, B_ROWS / 64, 2), 256, 0, stream>>>(
      h_img, h_txt, W1t_img, W1t_txt, b1_img, b1_txt, g_img, g_txt,
      DH, DENC);
  // head 2 + normalize fused -> fp8 reps8 directly
  head2_norm<<<dim3(B_ROWS / 16, 1, 2), 256, 0, stream>>>(
      g_img, g_txt, W2t_img, W2t_txt, b2_img, b2_txt, reps8);

  // sim partials via MX-fp8 K=128 MFMA (issue-ahead double-buffer)
  sim_fp8_kernel<<<dim3(NSLICE, NTOT / 256), 256, 0, stream>>>(reps8, Spart);
  // per-row loss (fp8-consistent corrections), no atomics
  rowfinal_kernel<<<NTOT / 4, 256, 0, stream>>>(reps8, Spart, L);
  // mean
  reduce_kernel<<<1, 1024, 0, stream>>>(L, (float*)d_out);
}